// Round 4
// baseline (306.541 us; speedup 1.0000x reference)
//
#include <hip/hip_runtime.h>

#define EPS 1e-12f
typedef __attribute__((ext_vector_type(8))) short short8;   // 8 x bf16
typedef __attribute__((ext_vector_type(4))) float f32x4;    // MFMA acc

#define MFMA(a, b, c) __builtin_amdgcn_mfma_f32_16x16x32_bf16(a, b, c, 0, 0, 0)

// ---- bf16 hi/lo split helpers (RNE hi, RNE lo), pair-packed ---------------
__device__ __forceinline__ unsigned rne16(unsigned u) {
  return u + 0x7FFFu + ((u >> 16) & 1u);
}
__device__ __forceinline__ void split_pair(float f0, float f1,
                                           unsigned& hp, unsigned& lp) {
  unsigned u0 = __float_as_uint(f0), u1 = __float_as_uint(f1);
  unsigned r0 = rne16(u0), r1 = rne16(u1);
  float h0 = __uint_as_float(r0 & 0xFFFF0000u);
  float h1 = __uint_as_float(r1 & 0xFFFF0000u);
  hp = (r0 >> 16) | (r1 & 0xFFFF0000u);
  unsigned v0 = rne16(__float_as_uint(f0 - h0));
  unsigned v1 = rne16(__float_as_uint(f1 - h1));
  lp = (v0 >> 16) | (v1 & 0xFFFF0000u);
}
__device__ __forceinline__ void split8(float4 a, float4 b, short8& h, short8& l) {
  union { unsigned u[4]; short8 s; } H, L;
  split_pair(a.x, a.y, H.u[0], L.u[0]);
  split_pair(a.z, a.w, H.u[1], L.u[1]);
  split_pair(b.x, b.y, H.u[2], L.u[2]);
  split_pair(b.z, b.w, H.u[3], L.u[3]);
  h = H.s; l = L.s;
}
__device__ __forceinline__ void split8f(const float* f, short8& h, short8& l) {
  union { unsigned u[4]; short8 s; } H, L;
  split_pair(f[0], f[1], H.u[0], L.u[0]);
  split_pair(f[2], f[3], H.u[1], L.u[1]);
  split_pair(f[4], f[5], H.u[2], L.u[2]);
  split_pair(f[6], f[7], H.u[3], L.u[3]);
  h = H.s; l = L.s;
}

// ---------------------------------------------------------------------------
// Prep: w [512 d][64 k] fp32 -> wT hi/lo bf16 [64 k][512 d]
// ---------------------------------------------------------------------------
extern "C" __global__ __launch_bounds__(256) void netvlad_prep(
    const float* __restrict__ w, unsigned short* __restrict__ wTh,
    unsigned short* __restrict__ wTl)
{
  int tg = blockIdx.x * 256 + threadIdx.x;   // = k*512 + d
  int k = tg >> 9, d = tg & 511;
  float f = w[d * 64 + k];
  unsigned u = __float_as_uint(f);
  unsigned rh = rne16(u);
  float hf = __uint_as_float(rh & 0xFFFF0000u);
  unsigned rl = rne16(__float_as_uint(f - hf));
  wTh[tg] = (unsigned short)(rh >> 16);
  wTl[tg] = (unsigned short)(rl >> 16);
}

// ---------------------------------------------------------------------------
// Kernel A: s = x@w (MFMA bf16-split, BARRIER-FREE K-loop: x and wT fragments
// read directly from global), softmax over K in registers, emit aT hi/lo bf16
// [b][64 k][1024 n] + asum. Block 256 thr / 4 waves; wave = 32 px x 64 k;
// block = 128 px. Grid 512 (2 blocks/CU).
// ---------------------------------------------------------------------------
extern "C" __global__ __launch_bounds__(256) void netvlad_assign(
    const float* __restrict__ x, const unsigned short* __restrict__ wTh,
    const unsigned short* __restrict__ wTl, unsigned short* __restrict__ aTh,
    unsigned short* __restrict__ aTl, float* __restrict__ asum)
{
  __shared__ unsigned short ath[64 * 136];  // aT tile [k][px], pad 136
  __shared__ unsigned short atl[64 * 136];
  __shared__ float asp[4 * 64];

  const int t = threadIdx.x;
  const int lane = t & 63, wv = t >> 6;
  const int lo4 = lane & 15, hi4 = lane >> 4;
  const int b = blockIdx.x >> 3;
  const int nblk = (blockIdx.x & 7) << 7;   // 128-px block within batch

  f32x4 acc[2][4] = {};

  // lane's A-row: px = blk*128 + wv*32 + pt*16 + lo4 ; d-chunk = hi4*8
  const float* xp0 =
      x + (size_t)((blockIdx.x << 7) + (wv << 5) + lo4) * 512 + (hi4 << 3);

  for (int d0 = 0; d0 < 512; d0 += 32) {
    short8 xh[2], xl[2];
#pragma unroll
    for (int pt = 0; pt < 2; ++pt) {
      const float* p = xp0 + (size_t)pt * (16 * 512) + d0;
      float4 v0 = *(const float4*)p;
      float4 v1 = *(const float4*)(p + 4);
      split8(v0, v1, xh[pt], xl[pt]);
    }
#pragma unroll
    for (int nt = 0; nt < 4; ++nt) {
      const size_t wo = (size_t)((nt << 4) + lo4) * 512 + d0 + (hi4 << 3);
      short8 wh = *(const short8*)(wTh + wo);
      short8 wl = *(const short8*)(wTl + wo);
#pragma unroll
      for (int pt = 0; pt < 2; ++pt) {
        acc[pt][nt] = MFMA(xh[pt], wh, acc[pt][nt]);
        acc[pt][nt] = MFMA(xl[pt], wh, acc[pt][nt]);
        acc[pt][nt] = MFMA(xh[pt], wl, acc[pt][nt]);
      }
    }
  }

  // softmax over k (4 nt regs x 16 lo4 lanes); px = wv*32 + pt*16 + hi4*4 + r
  float asum_p[4] = {0.f, 0.f, 0.f, 0.f};
#pragma unroll
  for (int pt = 0; pt < 2; ++pt) {
#pragma unroll
    for (int r = 0; r < 4; ++r) {
      float s0 = acc[pt][0][r], s1 = acc[pt][1][r];
      float s2 = acc[pt][2][r], s3 = acc[pt][3][r];
      float m = fmaxf(fmaxf(s0, s1), fmaxf(s2, s3));
      m = fmaxf(m, __shfl_xor(m, 1));
      m = fmaxf(m, __shfl_xor(m, 2));
      m = fmaxf(m, __shfl_xor(m, 4));
      m = fmaxf(m, __shfl_xor(m, 8));
      float e0 = __expf(s0 - m), e1 = __expf(s1 - m);
      float e2 = __expf(s2 - m), e3 = __expf(s3 - m);
      float s = e0 + e1 + e2 + e3;
      s += __shfl_xor(s, 1);
      s += __shfl_xor(s, 2);
      s += __shfl_xor(s, 4);
      s += __shfl_xor(s, 8);
      float inv = 1.0f / s;
      e0 *= inv; e1 *= inv; e2 *= inv; e3 *= inv;
      asum_p[0] += e0; asum_p[1] += e1; asum_p[2] += e2; asum_p[3] += e3;
      acc[pt][0][r] = e0; acc[pt][1][r] = e1;
      acc[pt][2][r] = e2; acc[pt][3][r] = e3;
    }
  }
  // scatter hi/lo into LDS transpose tiles
#pragma unroll
  for (int pt = 0; pt < 2; ++pt)
#pragma unroll
    for (int nt = 0; nt < 4; ++nt)
#pragma unroll
      for (int r = 0; r < 4; ++r) {
        float a = acc[pt][nt][r];
        unsigned u = __float_as_uint(a);
        unsigned rh = rne16(u);
        float hf = __uint_as_float(rh & 0xFFFF0000u);
        unsigned rl = rne16(__float_as_uint(a - hf));
        int idx = ((nt << 4) + lo4) * 136 + (wv << 5) + (pt << 4) + (hi4 << 2) + r;
        ath[idx] = (unsigned short)(rh >> 16);
        atl[idx] = (unsigned short)(rl >> 16);
      }
  // asum partials
#pragma unroll
  for (int nt = 0; nt < 4; ++nt) {
    float v = asum_p[nt];
    v += __shfl_xor(v, 16);
    v += __shfl_xor(v, 32);
    if (lane < 16) asp[(wv << 6) + (nt << 4) + lane] = v;
  }
  __syncthreads();
  if (t < 64) {
    float s = asp[t] + asp[64 + t] + asp[128 + t] + asp[192 + t];
    atomicAdd(&asum[(b << 6) + t], s);
  }
  // cooperative coalesced store: 64 k x 128 px
  {
    const int k = t >> 2, px0 = (t & 3) << 5;
    const size_t go = ((size_t)((b << 6) + k) << 10) + nblk + px0;
#pragma unroll
    for (int c = 0; c < 4; ++c) {
      *(short8*)(aTh + go + (c << 3)) = *(short8*)&ath[k * 136 + px0 + (c << 3)];
      *(short8*)(aTl + go + (c << 3)) = *(short8*)&atl[k * 136 + px0 + (c << 3)];
    }
  }
}

// ---------------------------------------------------------------------------
// Kernel B: vkd[b][d][k] = sum_n aT[k][n]*x[n][d] (MFMA bf16-split).
// Block 256 thr / 4 waves = 64 k x 64 d, n-loop 16 steps of 64.
// x tile staged ROW-major f32 in LDS (pad 68); transpose happens at the
// scalar fragment reads; split in registers. aT fragments direct from global
// (identical across the 4 waves -> L1 broadcast). Grid 512 (2 blocks/CU).
// ---------------------------------------------------------------------------
extern "C" __global__ __launch_bounds__(256) void netvlad_vlad(
    const float* __restrict__ x, const unsigned short* __restrict__ aTh,
    const unsigned short* __restrict__ aTl, float* __restrict__ vkd)
{
  __shared__ float xt[64 * 68];   // [n][d] f32, pad 68
  const int t = threadIdx.x;
  const int lane = t & 63, wv = t >> 6;
  const int lo4 = lane & 15, hi4 = lane >> 4;
  const int b = blockIdx.x >> 3;
  const int ds = (blockIdx.x & 7) << 6;     // 64-d slice
  const int srow = t >> 2, scol = (t & 3) << 4;
  const float* xs = x + ((size_t)(b << 10)) * 512 + ds;

  f32x4 acc[4] = {};

  for (int n0 = 0; n0 < 1024; n0 += 64) {
    __syncthreads();
    {
      const float* p = xs + (size_t)(n0 + srow) * 512 + scol;
      float4 v0 = ((const float4*)p)[0];
      float4 v1 = ((const float4*)p)[1];
      float4 v2 = ((const float4*)p)[2];
      float4 v3 = ((const float4*)p)[3];
      float* dst = &xt[srow * 68 + scol];
      ((float4*)dst)[0] = v0;
      ((float4*)dst)[1] = v1;
      ((float4*)dst)[2] = v2;
      ((float4*)dst)[3] = v3;
    }
    __syncthreads();
#pragma unroll
    for (int nf = 0; nf < 2; ++nf) {
      float f[8];
#pragma unroll
      for (int j = 0; j < 8; ++j)
        f[j] = xt[((nf << 5) + (hi4 << 3) + j) * 68 + (wv << 4) + lo4];
      short8 bh, bl;
      split8f(f, bh, bl);
#pragma unroll
      for (int kt = 0; kt < 4; ++kt) {
        const size_t ao = ((size_t)((b << 6) + (kt << 4) + lo4) << 10)
                        + n0 + (nf << 5) + (hi4 << 3);
        short8 ah = *(const short8*)(aTh + ao);
        short8 al = *(const short8*)(aTl + ao);
        acc[kt] = MFMA(ah, bh, acc[kt]);
        acc[kt] = MFMA(ah, bl, acc[kt]);
        acc[kt] = MFMA(al, bh, acc[kt]);
      }
    }
  }
  // D: row k = kt*16 + hi4*4 + r, col d = ds + wv*16 + lo4
#pragma unroll
  for (int kt = 0; kt < 4; ++kt) {
    float* vb = vkd + (((size_t)(b << 9) + ds + (wv << 4) + lo4) << 6)
              + (kt << 4) + (hi4 << 2);
    *(float4*)vb = make_float4(acc[kt][0], acc[kt][1], acc[kt][2], acc[kt][3]);
  }
}

// ---------------------------------------------------------------------------
// Kernel C1: v = vkd + asum[k]*C[d][k]; write out[b][d][k]; r_k partials.
// ---------------------------------------------------------------------------
extern "C" __global__ __launch_bounds__(256) void netvlad_fin1(
    const float* __restrict__ vkd, const float* __restrict__ Cm,
    const float* __restrict__ asum, float* __restrict__ out,
    float* __restrict__ r_buf)
{
  __shared__ float rp[4 * 64];
  const int t = threadIdx.x;
  const int k = t & 63;
  const int dg = t >> 6;
  const int b = blockIdx.x >> 2;
  const int dq = blockIdx.x & 3;
  const float asv = asum[b * 64 + k];
  const int dbase = dq * 128 + dg * 32;
  const float* p0 = vkd + (size_t)b * 512 * 64;
  float* ob = out + (size_t)b * 512 * 64;
  float racc = 0.f;
  for (int dd = 0; dd < 32; ++dd) {
    size_t off = (size_t)(dbase + dd) * 64 + k;
    float v = p0[off] + asv * Cm[off];
    ob[off] = v;
    racc = fmaf(v, v, racc);
  }
  rp[dg * 64 + k] = racc;
  __syncthreads();
  if (t < 64) {
    float r = rp[t] + rp[64 + t] + rp[128 + t] + rp[192 + t];
    atomicAdd(&r_buf[b * 64 + t], r);
  }
}

// ---------------------------------------------------------------------------
extern "C" __global__ __launch_bounds__(64) void netvlad_fin2(
    const float* __restrict__ r_buf, float* __restrict__ scale_buf)
{
  const int b = blockIdx.x;
  const int k = threadIdx.x;
  float r = r_buf[b * 64 + k];
  float g = r / (r + EPS);
  g += __shfl_xor(g, 1);
  g += __shfl_xor(g, 2);
  g += __shfl_xor(g, 4);
  g += __shfl_xor(g, 8);
  g += __shfl_xor(g, 16);
  g += __shfl_xor(g, 32);
  scale_buf[b * 64 + k] = 1.0f / (sqrtf(r + EPS) * sqrtf(g + EPS));
}

// ---------------------------------------------------------------------------
extern "C" __global__ __launch_bounds__(256) void netvlad_fin3(
    float* __restrict__ out, const float* __restrict__ scale_buf)
{
  __shared__ float sc[64];
  const int t = threadIdx.x;
  const int b = blockIdx.x >> 3;
  if (t < 64) sc[t] = scale_buf[b * 64 + t];
  __syncthreads();
  float4* o4 = (float4*)out;
#pragma unroll
  for (int c = 0; c < 4; ++c) {
    int idx = blockIdx.x * 1024 + c * 256 + t;
    float4 v = o4[idx];
    int k4 = (idx & 15) * 4;
    v.x *= sc[k4]; v.y *= sc[k4 + 1]; v.z *= sc[k4 + 2]; v.w *= sc[k4 + 3];
    o4[idx] = v;
  }
}

// ---------------------------------------------------------------------------
extern "C" void kernel_launch(void* const* d_in, const int* in_sizes, int n_in,
                              void* d_out, int out_size, void* d_ws,
                              size_t ws_size, hipStream_t stream)
{
  const float* x  = (const float*)d_in[0];  // [64,32,32,512]
  const float* w  = (const float*)d_in[1];  // [512,64]
  const float* Cm = (const float*)d_in[2];  // [512,64]
  float* out = (float*)d_out;               // [64, 512*64]

  // workspace carve: 25.3 MB total
  unsigned short* aTh = (unsigned short*)d_ws;            // 4,194,304 u16
  unsigned short* aTl = aTh + 4194304;                    // 4,194,304 u16
  float* vkd = (float*)(aTl + 4194304);                   // 2,097,152 f32
  unsigned short* wTh = (unsigned short*)(vkd + 2097152); // 32768 u16
  unsigned short* wTl = wTh + 32768;                      // 32768 u16
  float* asum = (float*)(wTl + 32768);                    // 4096 f32
  float* r_buf = asum + 4096;                             // 4096 f32
  float* scale_buf = r_buf + 4096;                        // 4096 f32

  hipMemsetAsync(asum, 0, 2 * 4096 * sizeof(float), stream);  // asum + r_buf

  netvlad_prep  <<<128, 256, 0, stream>>>(w, wTh, wTl);
  netvlad_assign<<<512, 256, 0, stream>>>(x, wTh, wTl, aTh, aTl, asum);
  netvlad_vlad  <<<512, 256, 0, stream>>>(x, aTh, aTl, vkd);
  netvlad_fin1  <<<256, 256, 0, stream>>>(vkd, Cm, asum, out, r_buf);
  netvlad_fin2  <<< 64,  64, 0, stream>>>(r_buf, scale_buf);
  netvlad_fin3  <<<512, 256, 0, stream>>>(out, scale_buf);
}

// Round 5
// 294.579 us; speedup vs baseline: 1.0406x; 1.0406x over previous
//
#include <hip/hip_runtime.h>

#define EPS 1e-12f
typedef __attribute__((ext_vector_type(8))) short short8;   // 8 x bf16
typedef __attribute__((ext_vector_type(4))) float f32x4;    // MFMA acc

#define MFMA(a, b, c) __builtin_amdgcn_mfma_f32_16x16x32_bf16(a, b, c, 0, 0, 0)

// ---- bf16 hi/lo split helpers (RNE hi, RNE lo) ----------------------------
__device__ __forceinline__ unsigned rne16(unsigned u) {
  return u + 0x7FFFu + ((u >> 16) & 1u);
}
__device__ __forceinline__ void split2(float f, unsigned short& h,
                                       unsigned short& l) {
  unsigned u = __float_as_uint(f);
  unsigned rh = rne16(u);
  float hf = __uint_as_float(rh & 0xFFFF0000u);
  unsigned rl = rne16(__float_as_uint(f - hf));
  h = (unsigned short)(rh >> 16);
  l = (unsigned short)(rl >> 16);
}
__device__ __forceinline__ void split_pair(float f0, float f1,
                                           unsigned& hp, unsigned& lp) {
  unsigned u0 = __float_as_uint(f0), u1 = __float_as_uint(f1);
  unsigned r0 = rne16(u0), r1 = rne16(u1);
  float h0 = __uint_as_float(r0 & 0xFFFF0000u);
  float h1 = __uint_as_float(r1 & 0xFFFF0000u);
  hp = (r0 >> 16) | (r1 & 0xFFFF0000u);
  unsigned v0 = rne16(__float_as_uint(f0 - h0));
  unsigned v1 = rne16(__float_as_uint(f1 - h1));
  lp = (v0 >> 16) | (v1 & 0xFFFF0000u);
}
__device__ __forceinline__ void split8(float4 a, float4 b, short8& h, short8& l) {
  union { unsigned u[4]; short8 s; } H, L;
  split_pair(a.x, a.y, H.u[0], L.u[0]);
  split_pair(a.z, a.w, H.u[1], L.u[1]);
  split_pair(b.x, b.y, H.u[2], L.u[2]);
  split_pair(b.z, b.w, H.u[3], L.u[3]);
  h = H.s; l = L.s;
}

// ---------------------------------------------------------------------------
// Prep: w [512 d][64 k] fp32 -> wT hi/lo bf16 [64 k][512 d]
// ---------------------------------------------------------------------------
extern "C" __global__ __launch_bounds__(256) void netvlad_prep(
    const float* __restrict__ w, unsigned short* __restrict__ wTh,
    unsigned short* __restrict__ wTl)
{
  int tg = blockIdx.x * 256 + threadIdx.x;   // = k*512 + d
  int k = tg >> 9, d = tg & 511;
  unsigned short h, l;
  split2(w[d * 64 + k], h, l);
  wTh[tg] = h;
  wTl[tg] = l;
}

// ---------------------------------------------------------------------------
// Kernel A: s = x@w (MFMA bf16-split), barrier-free K-loop with 1-iter x
// prefetch; softmax over K in registers; aT hi/lo bf16 [b][64 k][1024 n]
// + asum. Grid 1024 (4 blocks/CU), block = 4 waves x 16 px = 64 px.
// ---------------------------------------------------------------------------
extern "C" __global__ __launch_bounds__(256) void netvlad_assign(
    const float* __restrict__ x, const unsigned short* __restrict__ wTh,
    const unsigned short* __restrict__ wTl, unsigned short* __restrict__ aTh,
    unsigned short* __restrict__ aTl, float* __restrict__ asum)
{
  __shared__ unsigned short ath[64 * 72];  // aT tile [k][px], pad 72
  __shared__ unsigned short atl[64 * 72];
  __shared__ float asp[4 * 64];

  const int t = threadIdx.x;
  const int lane = t & 63, wv = t >> 6;
  const int lo4 = lane & 15, hi4 = lane >> 4;
  const int b = blockIdx.x >> 4;
  const int nblk = (blockIdx.x & 15) << 6;   // 64-px block within batch

  f32x4 acc[4] = {};

  // lane's A-row: px = blk*64 + wv*16 + lo4 ; d-chunk = hi4*8
  const float* xp =
      x + ((size_t)(blockIdx.x << 6) + (wv << 4) + lo4) * 512 + (hi4 << 3);

  float4 c0 = *(const float4*)xp;
  float4 c1 = *(const float4*)(xp + 4);
  for (int d0 = 0; d0 < 512; d0 += 32) {
    // prefetch next chunk (wraps to 0 on last iter; harmless L1 hit)
    const float* np = xp + ((d0 < 480) ? d0 + 32 : 0);
    float4 n0v = *(const float4*)np;
    float4 n1v = *(const float4*)(np + 4);
    short8 xh, xl;
    split8(c0, c1, xh, xl);
#pragma unroll
    for (int nt = 0; nt < 4; ++nt) {
      const size_t wo = (size_t)((nt << 4) + lo4) * 512 + d0 + (hi4 << 3);
      short8 wh = *(const short8*)(wTh + wo);
      short8 wl = *(const short8*)(wTl + wo);
      acc[nt] = MFMA(xh, wh, acc[nt]);
      acc[nt] = MFMA(xl, wh, acc[nt]);
      acc[nt] = MFMA(xh, wl, acc[nt]);
    }
    c0 = n0v; c1 = n1v;
  }

  // softmax over k (4 nt regs x 16 lo4 lanes); px = wv*16 + hi4*4 + r
  float asum_p[4] = {0.f, 0.f, 0.f, 0.f};
#pragma unroll
  for (int r = 0; r < 4; ++r) {
    float s0 = acc[0][r], s1 = acc[1][r], s2 = acc[2][r], s3 = acc[3][r];
    float m = fmaxf(fmaxf(s0, s1), fmaxf(s2, s3));
    m = fmaxf(m, __shfl_xor(m, 1));
    m = fmaxf(m, __shfl_xor(m, 2));
    m = fmaxf(m, __shfl_xor(m, 4));
    m = fmaxf(m, __shfl_xor(m, 8));
    float e0 = __expf(s0 - m), e1 = __expf(s1 - m);
    float e2 = __expf(s2 - m), e3 = __expf(s3 - m);
    float s = e0 + e1 + e2 + e3;
    s += __shfl_xor(s, 1);
    s += __shfl_xor(s, 2);
    s += __shfl_xor(s, 4);
    s += __shfl_xor(s, 8);
    float inv = 1.0f / s;
    e0 *= inv; e1 *= inv; e2 *= inv; e3 *= inv;
    asum_p[0] += e0; asum_p[1] += e1; asum_p[2] += e2; asum_p[3] += e3;
    acc[0][r] = e0; acc[1][r] = e1; acc[2][r] = e2; acc[3][r] = e3;
  }
  // scatter hi/lo into LDS transpose tile
#pragma unroll
  for (int nt = 0; nt < 4; ++nt)
#pragma unroll
    for (int r = 0; r < 4; ++r) {
      unsigned short h, l;
      split2(acc[nt][r], h, l);
      int idx = ((nt << 4) + lo4) * 72 + (wv << 4) + (hi4 << 2) + r;
      ath[idx] = h;
      atl[idx] = l;
    }
  // asum partials
#pragma unroll
  for (int nt = 0; nt < 4; ++nt) {
    float v = asum_p[nt];
    v += __shfl_xor(v, 16);
    v += __shfl_xor(v, 32);
    if (lane < 16) asp[(wv << 6) + (nt << 4) + lane] = v;
  }
  __syncthreads();
  if (t < 64) {
    float s = asp[t] + asp[64 + t] + asp[128 + t] + asp[192 + t];
    atomicAdd(&asum[(b << 6) + t], s);
  }
  // cooperative coalesced store: 64 k x 64 px
  {
    const int k = t >> 2, px0 = (t & 3) << 4;
    const size_t go = ((size_t)((b << 6) + k) << 10) + nblk + px0;
    *(short8*)(aTh + go)     = *(short8*)&ath[k * 72 + px0];
    *(short8*)(aTh + go + 8) = *(short8*)&ath[k * 72 + px0 + 8];
    *(short8*)(aTl + go)     = *(short8*)&atl[k * 72 + px0];
    *(short8*)(aTl + go + 8) = *(short8*)&atl[k * 72 + px0 + 8];
  }
}

// ---------------------------------------------------------------------------
// Kernel B: vkd[b][d][k] = sum_n aT[k][n]*x[n][d] (MFMA bf16-split).
// Grid 1024 = 64 b x 16 d-slices(32). Block 4 waves; wave = 16 k x 32 d.
// x staged pre-split + transposed into LDS u16 (b128 fragment reads),
// single-barrier double buffer, 1-iter global prefetch. aT direct global.
// ---------------------------------------------------------------------------
extern "C" __global__ __launch_bounds__(256) void netvlad_vlad(
    const float* __restrict__ x, const unsigned short* __restrict__ aTh,
    const unsigned short* __restrict__ aTl, float* __restrict__ vkd)
{
  __shared__ unsigned short xth[2][32 * 72];   // xT [d][n] u16, pad 72
  __shared__ unsigned short xtl[2][32 * 72];
  const int t = threadIdx.x;
  const int lane = t & 63, wv = t >> 6;
  const int lo4 = lane & 15, hi4 = lane >> 4;
  const int b = blockIdx.x >> 4;
  const int ds = (blockIdx.x & 15) << 5;    // 32-d slice
  const int tn = t & 63;                    // staging n
  const int tdc = (t >> 6) << 3;            // staging d-chunk (8)
  const float* xsb = x + ((size_t)(b << 10)) * 512 + ds + tdc;

  f32x4 acc[2] = {};

  float4 r0 = *(const float4*)(xsb + (size_t)tn * 512);
  float4 r1 = *(const float4*)(xsb + (size_t)tn * 512 + 4);

  for (int it = 0; it < 16; ++it) {
    const int n0 = it << 6;
    unsigned short* th = xth[it & 1];
    unsigned short* tl = xtl[it & 1];
    // split current regs, scatter transposed (2 lanes/dword -> free)
    float f[8] = {r0.x, r0.y, r0.z, r0.w, r1.x, r1.y, r1.z, r1.w};
#pragma unroll
    for (int j = 0; j < 8; ++j) {
      unsigned short h, l;
      split2(f[j], h, l);
      th[(tdc + j) * 72 + tn] = h;
      tl[(tdc + j) * 72 + tn] = l;
    }
    __syncthreads();
    if (it < 15) {
      const float* p = xsb + (size_t)(n0 + 64 + tn) * 512;
      r0 = *(const float4*)p;
      r1 = *(const float4*)(p + 4);
    }
#pragma unroll
    for (int nf = 0; nf < 2; ++nf) {
      const size_t ao = ((size_t)((b << 6) + (wv << 4) + lo4) << 10)
                      + n0 + (nf << 5) + (hi4 << 3);
      short8 ah = *(const short8*)(aTh + ao);
      short8 al = *(const short8*)(aTl + ao);
#pragma unroll
      for (int dt = 0; dt < 2; ++dt) {
        const int xo = ((dt << 4) + lo4) * 72 + (nf << 5) + (hi4 << 3);
        short8 bh = *(short8*)&th[xo];
        short8 bl = *(short8*)&tl[xo];
        acc[dt] = MFMA(ah, bh, acc[dt]);
        acc[dt] = MFMA(ah, bl, acc[dt]);
        acc[dt] = MFMA(al, bh, acc[dt]);
      }
    }
  }
  // D: row k = wv*16 + hi4*4 + r, col d = ds + dt*16 + lo4
#pragma unroll
  for (int dt = 0; dt < 2; ++dt) {
    float* vb = vkd + (((size_t)(b << 9) + ds + (dt << 4) + lo4) << 6)
              + (wv << 4) + (hi4 << 2);
    *(float4*)vb = make_float4(acc[dt][0], acc[dt][1], acc[dt][2], acc[dt][3]);
  }
}

// ---------------------------------------------------------------------------
// Kernel C1: v = vkd + asum[k]*C[d][k]; write out[b][d][k]; r_k partials.
// Grid 1024 = 64 b x 16 d-slices(32); float4 I/O.
// ---------------------------------------------------------------------------
extern "C" __global__ __launch_bounds__(256) void netvlad_fin1(
    const float* __restrict__ vkd, const float* __restrict__ Cm,
    const float* __restrict__ asum, float* __restrict__ out,
    float* __restrict__ r_buf)
{
  __shared__ float rp[16 * 64];
  const int t = threadIdx.x;
  const int b = blockIdx.x >> 4;
  const int ds = (blockIdx.x & 15) << 5;
  const int k4 = (t & 15) << 2;
  const int dg = t >> 4;                 // 0..15
  float4 asv = *(const float4*)(asum + (b << 6) + k4);
  float4 racc = {0.f, 0.f, 0.f, 0.f};
#pragma unroll
  for (int j = 0; j < 2; ++j) {
    int d = ds + dg * 2 + j;
    size_t off = (((size_t)(b << 9) + d) << 6) + k4;
    float4 v = *(const float4*)(vkd + off);
    float4 c = *(const float4*)(Cm + ((size_t)d << 6) + k4);
    v.x += asv.x * c.x; v.y += asv.y * c.y;
    v.z += asv.z * c.z; v.w += asv.w * c.w;
    *(float4*)(out + off) = v;
    racc.x = fmaf(v.x, v.x, racc.x); racc.y = fmaf(v.y, v.y, racc.y);
    racc.z = fmaf(v.z, v.z, racc.z); racc.w = fmaf(v.w, v.w, racc.w);
  }
  *(float4*)&rp[dg * 64 + k4] = racc;
  __syncthreads();
  if (t < 64) {
    float r = 0.f;
#pragma unroll
    for (int g = 0; g < 16; ++g) r += rp[g * 64 + t];
    atomicAdd(&r_buf[(b << 6) + t], r);
  }
}

// ---------------------------------------------------------------------------
// Kernel C3: compute per-batch scales from r_buf (redundantly per block,
// wave 0) and apply: out *= scale[k]. Grid 512 (8 blocks/batch).
// ---------------------------------------------------------------------------
extern "C" __global__ __launch_bounds__(256) void netvlad_fin3(
    float* __restrict__ out, const float* __restrict__ r_buf)
{
  __shared__ float sc[64];
  const int t = threadIdx.x;
  const int b = blockIdx.x >> 3;
  if (t < 64) {
    float r = r_buf[(b << 6) + t];
    float g = r / (r + EPS);
    g += __shfl_xor(g, 1);
    g += __shfl_xor(g, 2);
    g += __shfl_xor(g, 4);
    g += __shfl_xor(g, 8);
    g += __shfl_xor(g, 16);
    g += __shfl_xor(g, 32);
    sc[t] = 1.0f / (sqrtf(r + EPS) * sqrtf(g + EPS));
  }
  __syncthreads();
  float4* o4 = (float4*)out;
#pragma unroll
  for (int c = 0; c < 4; ++c) {
    int idx = blockIdx.x * 1024 + c * 256 + t;
    float4 v = o4[idx];
    int k4 = (idx & 15) * 4;
    v.x *= sc[k4]; v.y *= sc[k4 + 1]; v.z *= sc[k4 + 2]; v.w *= sc[k4 + 3];
    o4[idx] = v;
  }
}

// ---------------------------------------------------------------------------
extern "C" void kernel_launch(void* const* d_in, const int* in_sizes, int n_in,
                              void* d_out, int out_size, void* d_ws,
                              size_t ws_size, hipStream_t stream)
{
  const float* x  = (const float*)d_in[0];  // [64,32,32,512]
  const float* w  = (const float*)d_in[1];  // [512,64]
  const float* Cm = (const float*)d_in[2];  // [512,64]
  float* out = (float*)d_out;               // [64, 512*64]

  // workspace carve: ~25.3 MB total
  unsigned short* aTh = (unsigned short*)d_ws;            // 4,194,304 u16
  unsigned short* aTl = aTh + 4194304;                    // 4,194,304 u16
  float* vkd = (float*)(aTl + 4194304);                   // 2,097,152 f32
  unsigned short* wTh = (unsigned short*)(vkd + 2097152); // 32768 u16
  unsigned short* wTl = wTh + 32768;                      // 32768 u16
  float* asum = (float*)(wTl + 32768);                    // 4096 f32
  float* r_buf = asum + 4096;                             // 4096 f32

  hipMemsetAsync(asum, 0, 2 * 4096 * sizeof(float), stream);  // asum + r_buf

  netvlad_prep  <<< 128, 256, 0, stream>>>(w, wTh, wTl);
  netvlad_assign<<<1024, 256, 0, stream>>>(x, wTh, wTl, aTh, aTl, asum);
  netvlad_vlad  <<<1024, 256, 0, stream>>>(x, aTh, aTl, vkd);
  netvlad_fin1  <<<1024, 256, 0, stream>>>(vkd, Cm, asum, out, r_buf);
  netvlad_fin3  <<< 512, 256, 0, stream>>>(out, r_buf);
}